// Round 2
// baseline (244.232 us; speedup 1.0000x reference)
//
#include <hip/hip_runtime.h>
#include <hip/hip_bf16.h>

// SpaAggregator: out[b, :] = (1/K) * sum_k table[idx[b, k], :]
//   table: [V, D] fp32 (V=200000, D=128 -> 102.4 MB, fits in 256 MiB L3)
//   idx:   [B, K] int   (B=50000, K=32)
//   out:   [B, D] fp32
//
// One wave handles TWO nodes (doubles memory-level parallelism vs round 1):
//   chunk = lane & 31 -> which float4 of the 128-float row
//   sub   = lane >> 5 -> which half of the K neighbors this lane sums
//   Each lane loads one index (64 lanes = 2 nodes x K=32), broadcast via
//   __shfl. Inner loop issues 32 independent global_load_dwordx4 per lane
//   (16 per node, interleaved) before any accumulation -> 2x outstanding
//   loads per wave vs round 1. Halves combined with __shfl_xor(32);
//   lanes 0..31 store coalesced float4 for both nodes.

#define FEAT_D 128            // floats per row
#define CHUNKS (FEAT_D / 4)   // 32 float4 chunks per row

__global__ __launch_bounds__(256) void spa_gather_mean2(
    const float* __restrict__ table,
    const int* __restrict__ idx,
    float* __restrict__ out,
    int B, int K, float invK)
{
    const int wave = threadIdx.x >> 6;               // 0..3
    const int lane = threadIdx.x & 63;
    const int pair = blockIdx.x * 4 + wave;          // which node-pair
    const int node0 = pair * 2;
    const int node1 = node0 + 1;
    if (node0 >= B) return;

    const int chunk = lane & 31;                     // float4 index in row
    const int sub   = lane >> 5;                     // 0 or 1

    const float4* __restrict__ tbl4 = (const float4*)table;

    float4 acc0 = make_float4(0.f, 0.f, 0.f, 0.f);
    float4 acc1 = make_float4(0.f, 0.f, 0.f, 0.f);

    if (K == 32 && node1 < B) {
        // Fast path: lane l holds idx[node0*32 + l] for l<32, idx[node1*32 + (l-32)] for l>=32.
        const int my_idx = idx[(long)node0 * 32 + lane];

        #pragma unroll
        for (int i = 0; i < 16; ++i) {
            const int k = 2 * i + sub;
            const int row0 = __shfl(my_idx, k);        // node0's k-th neighbor
            const int row1 = __shfl(my_idx, 32 + k);   // node1's k-th neighbor
            const float4 v0 = tbl4[(long)(row0 * CHUNKS + chunk)];
            const float4 v1 = tbl4[(long)(row1 * CHUNKS + chunk)];
            acc0.x += v0.x; acc0.y += v0.y; acc0.z += v0.z; acc0.w += v0.w;
            acc1.x += v1.x; acc1.y += v1.y; acc1.z += v1.z; acc1.w += v1.w;
        }
    } else {
        // General path (tail pair or K != 32): one node at a time.
        for (int n = node0; n <= node1 && n < B; ++n) {
            int my_idx = 0;
            if (chunk < K) my_idx = idx[(long)n * K + chunk];
            float4 a = make_float4(0.f, 0.f, 0.f, 0.f);
            for (int k = sub; k < K; k += 2) {
                const int row = __shfl(my_idx, k);
                const float4 v = tbl4[(long)row * CHUNKS + chunk];
                a.x += v.x; a.y += v.y; a.z += v.z; a.w += v.w;
            }
            if (n == node0) acc0 = a; else acc1 = a;
        }
    }

    // Combine the two neighbor-halves (lane l <-> lane l^32).
    acc0.x += __shfl_xor(acc0.x, 32);
    acc0.y += __shfl_xor(acc0.y, 32);
    acc0.z += __shfl_xor(acc0.z, 32);
    acc0.w += __shfl_xor(acc0.w, 32);
    acc1.x += __shfl_xor(acc1.x, 32);
    acc1.y += __shfl_xor(acc1.y, 32);
    acc1.z += __shfl_xor(acc1.z, 32);
    acc1.w += __shfl_xor(acc1.w, 32);

    if (sub == 0) {
        float4 r0;
        r0.x = acc0.x * invK; r0.y = acc0.y * invK;
        r0.z = acc0.z * invK; r0.w = acc0.w * invK;
        ((float4*)out)[(long)node0 * CHUNKS + chunk] = r0;
        if (node1 < B) {
            float4 r1;
            r1.x = acc1.x * invK; r1.y = acc1.y * invK;
            r1.z = acc1.z * invK; r1.w = acc1.w * invK;
            ((float4*)out)[(long)node1 * CHUNKS + chunk] = r1;
        }
    }
}

extern "C" void kernel_launch(void* const* d_in, const int* in_sizes, int n_in,
                              void* d_out, int out_size, void* d_ws, size_t ws_size,
                              hipStream_t stream)
{
    const float* table = (const float*)d_in[0];
    const int*   idx   = (const int*)d_in[1];

    float* out = (float*)d_out;

    const int B = out_size / FEAT_D;          // out is [B, 128]
    const int K = in_sizes[1] / B;            // idx is [B, K]
    const float invK = 1.0f / (float)K;

    // 4 waves/block, 2 nodes/wave -> 8 nodes per block.
    const int pairs = (B + 1) / 2;
    const int grid = (pairs + 3) / 4;

    spa_gather_mean2<<<grid, 256, 0, stream>>>(table, idx, out, B, K, invK);
}